// Round 1
// baseline (119.109 us; speedup 1.0000x reference)
//
#include <hip/hip_runtime.h>

// DKNN via NeuralSort relaxation — round 4 (fusion + barrier-collapse).
// query [32,128] f32, neighbors [1024,128] f32, gumbel [2,32,1024] f32.
// out [2,32,1024] f32 = sum of first K=16 rows of relaxed perm matrix.
//
// Numerics are FROZEN (absmax pinned at 0.0234375 by the harness's bf16
// compare). Every accumulation in this round is order-identical to R3:
//  - s: same per-row a0..a3 stride-4 f64 loop, same (a0+a1)+(a2+a3) combine.
//  - B: same per-quarter a0..a3 stride-4 |s_j-s_i| sums, same
//       (q0+q1)+(q2+q3) final combine that R3's k_soft applied to Bq.
//  - softmax: identical fma/expf expressions, identical per-thread e-sum
//       order, identical shfl tree + 4-wave combine, identical r-sequential
//       acc order. t/e are recomputed (bit-deterministic) instead of stored.
// => output is bitwise-identical to R3.
//
// R4 theory: work floor is ~10-15us (134M f64 ops, all L2-resident); the
// 82.5us was launch serialization (3 dependent dispatches) + k_soft's 48
// block barriers (16 ranks x 3 syncthreads). This round: 2 dispatches,
// k_soft down to 2 barriers.

constexpr int NN = 1024;   // neighbors
constexpr int ND = 128;    // dims
constexpr int NP = 64;     // samples(2) * queries(32)
constexpr int KTOP = 16;

// ---------------------------------------------------------------- kernel 1
// Fused scores + B. 256 blocks x 256 thr, block = (p, jc).
// Each block redundantly computes the FULL s row for its p into LDS (4 rows
// per thread, bitwise-identical inner loop to R3's k_scores), then computes
// B for its 256-j quarter entirely from LDS (R3 k_bsum order), and writes
// s (own quarter) + final-combined B to the workspace for kernel 2.
__global__ __launch_bounds__(256) void k_sb(const float* __restrict__ q,
                                            const float* __restrict__ nb,
                                            const float* __restrict__ gum,
                                            double* __restrict__ s_out,
                                            double* __restrict__ b_out) {
  int b = blockIdx.x;
  int p = b >> 2, jc = b & 3;
  int m = p & 31;
  __shared__ double qs[ND];
  __shared__ double ss[NN];
  int tid = threadIdx.x;
  if (tid < ND) qs[tid] = (double)q[m * ND + tid];
  __syncthreads();
  // ---- phase A: all 1024 s values for this p (4x redundant across jc blocks,
  // but keeps phase B on all 256 CUs; neighbors are L2-resident).
#pragma unroll
  for (int c = 0; c < 4; ++c) {
    int j = c * 256 + tid;
    const float4* nrow = (const float4*)(nb + (size_t)j * ND);
    double a0 = 0.0, a1 = 0.0, a2 = 0.0, a3 = 0.0;
#pragma unroll
    for (int d4 = 0; d4 < ND / 4; ++d4) {
      float4 n4 = nrow[d4];
      double d0 = qs[d4 * 4 + 0] - (double)n4.x;
      double d1 = qs[d4 * 4 + 1] - (double)n4.y;
      double d2 = qs[d4 * 4 + 2] - (double)n4.z;
      double d3 = qs[d4 * 4 + 3] - (double)n4.w;
      a0 += d0 * d0; a1 += d1 * d1; a2 += d2 * d2; a3 += d3 * d3;
    }
    ss[j] = (double)gum[(size_t)p * NN + j] - ((a0 + a1) + (a2 + a3));
  }
  __syncthreads();
  // ---- phase B: B_j for this block's quarter, straight from LDS.
  int j = jc * 256 + tid;
  double sj = ss[j];
  s_out[(size_t)p * NN + j] = sj;  // this block owns quarter jc's s write
  double qsum[4];
#pragma unroll
  for (int iq = 0; iq < 4; ++iq) {
    const double* sq = ss + iq * 256;
    double a0 = 0.0, a1 = 0.0, a2 = 0.0, a3 = 0.0;
#pragma unroll 4
    for (int i = 0; i < 256; i += 4) {
      a0 += fabs(sj - sq[i + 0]);
      a1 += fabs(sj - sq[i + 1]);
      a2 += fabs(sj - sq[i + 2]);
      a3 += fabs(sj - sq[i + 3]);
    }
    qsum[iq] = (a0 + a1) + (a2 + a3);
  }
  // same combine order R3's k_soft used on the four Bq quarters
  b_out[(size_t)p * NN + j] = (qsum[0] + qsum[1]) + (qsum[2] + qsum[3]);
}

// ---------------------------------------------------------------- kernel 2
// Softmax-topk with 2 barriers total (was 48): pass 1 reduces all 16 row
// maxes at once; pass 2 reduces all 16 Z's at once; pass 3 accumulates in
// the original r order. t and e are recomputed per pass — identical fp ops
// => identical bits.
__global__ __launch_bounds__(256) void k_soft(const double* __restrict__ s,
                                              const double* __restrict__ Bv,
                                              float* __restrict__ out) {
  int p = blockIdx.x;
  int tid = threadIdx.x;
  int wave = tid >> 6, lane = tid & 63;
  size_t base = (size_t)p * NN;
  double sj[4], bj[4];
  float acc[4];
#pragma unroll
  for (int k = 0; k < 4; ++k) {
    size_t idx = base + tid + k * 256;
    sj[k] = s[idx];
    bj[k] = Bv[idx];
    acc[k] = 0.f;
  }
  __shared__ float redm[KTOP][4];
  __shared__ float redz[KTOP][4];
  // ---- pass 1: per-thread maxes for all 16 ranks, one batched reduction
  float mx[KTOP];
#pragma unroll
  for (int r = 0; r < KTOP; ++r) {
    double cr = (double)(1023 - 2 * r);
    float mv = -3.4e38f;
#pragma unroll
    for (int k = 0; k < 4; ++k) mv = fmaxf(mv, (float)fma(cr, sj[k], -bj[k]));
    mx[r] = mv;
  }
#pragma unroll
  for (int off = 32; off; off >>= 1) {
#pragma unroll
    for (int r = 0; r < KTOP; ++r)
      mx[r] = fmaxf(mx[r], __shfl_down(mx[r], off, 64));
  }
  if (lane == 0) {
#pragma unroll
    for (int r = 0; r < KTOP; ++r) redm[r][wave] = mx[r];
  }
  __syncthreads();
  float mf[KTOP];
#pragma unroll
  for (int r = 0; r < KTOP; ++r)
    mf[r] = fmaxf(fmaxf(redm[r][0], redm[r][1]),
                  fmaxf(redm[r][2], redm[r][3]));
  // ---- pass 2: per-thread Z partials for all 16 ranks, one batched reduction
  float zz[KTOP];
#pragma unroll
  for (int r = 0; r < KTOP; ++r) {
    double cr = (double)(1023 - 2 * r);
    double md = (double)mf[r];
    float z = 0.f;
#pragma unroll
    for (int k = 0; k < 4; ++k)
      z += __expf((float)(fma(cr, sj[k], -bj[k]) - md));
    zz[r] = z;
  }
#pragma unroll
  for (int off = 32; off; off >>= 1) {
#pragma unroll
    for (int r = 0; r < KTOP; ++r) zz[r] += __shfl_down(zz[r], off, 64);
  }
  if (lane == 0) {
#pragma unroll
    for (int r = 0; r < KTOP; ++r) redz[r][wave] = zz[r];
  }
  __syncthreads();
  // ---- pass 3: accumulate in original r order (bitwise-identical acc)
#pragma unroll
  for (int r = 0; r < KTOP; ++r) {
    double cr = (double)(1023 - 2 * r);
    double md = (double)mf[r];
    float iZ = 1.0f / ((redz[r][0] + redz[r][1]) + (redz[r][2] + redz[r][3]));
#pragma unroll
    for (int k = 0; k < 4; ++k)
      acc[k] += __expf((float)(fma(cr, sj[k], -bj[k]) - md)) * iZ;
  }
#pragma unroll
  for (int k = 0; k < 4; ++k) out[base + tid + k * 256] = acc[k];
}

extern "C" void kernel_launch(void* const* d_in, const int* in_sizes, int n_in,
                              void* d_out, int out_size, void* d_ws, size_t ws_size,
                              hipStream_t stream) {
  const float* q   = (const float*)d_in[0];   // [32,128]
  const float* nb  = (const float*)d_in[1];   // [1024,128]
  const float* gum = (const float*)d_in[2];   // [2,32,1024]
  float* out = (float*)d_out;                 // [2,32,1024]

  char* ws = (char*)d_ws;
  double* s = (double*)ws;                          // 512 KiB
  double* B = (double*)(ws + (size_t)NP * NN * 8);  // 512 KiB

  k_sb<<<256, 256, 0, stream>>>(q, nb, gum, s, B);
  k_soft<<<NP, 256, 0, stream>>>(s, B, out);
}

// Round 2
// 89.349 us; speedup vs baseline: 1.3331x; 1.3331x over previous
//
#include <hip/hip_runtime.h>

// DKNN via NeuralSort relaxation — round 5 (spill fix).
// query [32,128] f32, neighbors [1024,128] f32, gumbel [2,32,1024] f32.
// out [2,32,1024] f32 = sum of first K=16 rows of relaxed perm matrix.
//
// Numerics are FROZEN (absmax pinned at 0.0234375, bf16 compare). All
// accumulation chains (a0..a3 stride-4 sums, (a0+a1)+(a2+a3) combines,
// (q0+q1)+(q2+q3) B combine, softmax shfl tree + 4-wave combine, r-order
// acc) are unchanged from R3/R4 => bitwise-identical output.
//
// R4 post-mortem: k_sb hit VGPR_Count=256 + 63 MiB of scratch-spill writes
// (WRITE_SIZE counter) because `#pragma unroll` on the phase-A c-loop fully
// unrolled 4x32 float4 loads. R5: `#pragma unroll 1` on the c-loop,
// partial unroll 8 inside, __launch_bounds__(256,4) to cap at 128 VGPRs.
// Unroll factors don't reorder the sequential dependence chains => same bits.

constexpr int NN = 1024;   // neighbors
constexpr int ND = 128;    // dims
constexpr int NP = 64;     // samples(2) * queries(32)
constexpr int KTOP = 16;

// ---------------------------------------------------------------- kernel 1
// Fused scores + B. 256 blocks x 256 thr, block = (p, jc).
// Each block redundantly computes the FULL s row for its p into LDS
// (bitwise-identical inner loop to R3's k_scores), then computes B for its
// 256-j quarter from LDS (R3 k_bsum order) and writes s + combined B.
__global__ __launch_bounds__(256, 4) void k_sb(const float* __restrict__ q,
                                               const float* __restrict__ nb,
                                               const float* __restrict__ gum,
                                               double* __restrict__ s_out,
                                               double* __restrict__ b_out) {
  int b = blockIdx.x;
  int p = b >> 2, jc = b & 3;
  int m = p & 31;
  __shared__ double qs[ND];
  __shared__ double ss[NN];
  int tid = threadIdx.x;
  if (tid < ND) qs[tid] = (double)q[m * ND + tid];
  __syncthreads();
  // ---- phase A: all 1024 s values for this p (4x redundant across jc
  // blocks; neighbors are L2-resident so the redundancy is cheap and keeps
  // phase B on all 256 CUs). unroll 1: keep register pressure low (R4 spill).
#pragma unroll 1
  for (int c = 0; c < 4; ++c) {
    int j = c * 256 + tid;
    const float4* nrow = (const float4*)(nb + (size_t)j * ND);
    double a0 = 0.0, a1 = 0.0, a2 = 0.0, a3 = 0.0;
#pragma unroll 8
    for (int d4 = 0; d4 < ND / 4; ++d4) {
      float4 n4 = nrow[d4];
      double d0 = qs[d4 * 4 + 0] - (double)n4.x;
      double d1 = qs[d4 * 4 + 1] - (double)n4.y;
      double d2 = qs[d4 * 4 + 2] - (double)n4.z;
      double d3 = qs[d4 * 4 + 3] - (double)n4.w;
      a0 += d0 * d0; a1 += d1 * d1; a2 += d2 * d2; a3 += d3 * d3;
    }
    ss[j] = (double)gum[(size_t)p * NN + j] - ((a0 + a1) + (a2 + a3));
  }
  __syncthreads();
  // ---- phase B: B_j for this block's quarter, straight from LDS.
  int j = jc * 256 + tid;
  double sj = ss[j];
  s_out[(size_t)p * NN + j] = sj;  // this block owns quarter jc's s write
  double qsum[4];
#pragma unroll 1
  for (int iq = 0; iq < 4; ++iq) {
    const double* sq = ss + iq * 256;
    double a0 = 0.0, a1 = 0.0, a2 = 0.0, a3 = 0.0;
#pragma unroll 4
    for (int i = 0; i < 256; i += 4) {
      a0 += fabs(sj - sq[i + 0]);
      a1 += fabs(sj - sq[i + 1]);
      a2 += fabs(sj - sq[i + 2]);
      a3 += fabs(sj - sq[i + 3]);
    }
    qsum[iq] = (a0 + a1) + (a2 + a3);
  }
  // same combine order R3's k_soft used on the four Bq quarters
  b_out[(size_t)p * NN + j] = (qsum[0] + qsum[1]) + (qsum[2] + qsum[3]);
}

// ---------------------------------------------------------------- kernel 2
// Softmax-topk with 2 barriers total: pass 1 reduces all 16 row maxes at
// once; pass 2 reduces all 16 Z's at once; pass 3 accumulates in original
// r order. t/e recomputed per pass — identical fp ops => identical bits.
__global__ __launch_bounds__(256) void k_soft(const double* __restrict__ s,
                                              const double* __restrict__ Bv,
                                              float* __restrict__ out) {
  int p = blockIdx.x;
  int tid = threadIdx.x;
  int wave = tid >> 6, lane = tid & 63;
  size_t base = (size_t)p * NN;
  double sj[4], bj[4];
  float acc[4];
#pragma unroll
  for (int k = 0; k < 4; ++k) {
    size_t idx = base + tid + k * 256;
    sj[k] = s[idx];
    bj[k] = Bv[idx];
    acc[k] = 0.f;
  }
  __shared__ float redm[KTOP][4];
  __shared__ float redz[KTOP][4];
  // ---- pass 1: per-thread maxes for all 16 ranks, one batched reduction
  float mx[KTOP];
#pragma unroll
  for (int r = 0; r < KTOP; ++r) {
    double cr = (double)(1023 - 2 * r);
    float mv = -3.4e38f;
#pragma unroll
    for (int k = 0; k < 4; ++k) mv = fmaxf(mv, (float)fma(cr, sj[k], -bj[k]));
    mx[r] = mv;
  }
#pragma unroll
  for (int off = 32; off; off >>= 1) {
#pragma unroll
    for (int r = 0; r < KTOP; ++r)
      mx[r] = fmaxf(mx[r], __shfl_down(mx[r], off, 64));
  }
  if (lane == 0) {
#pragma unroll
    for (int r = 0; r < KTOP; ++r) redm[r][wave] = mx[r];
  }
  __syncthreads();
  float mf[KTOP];
#pragma unroll
  for (int r = 0; r < KTOP; ++r)
    mf[r] = fmaxf(fmaxf(redm[r][0], redm[r][1]),
                  fmaxf(redm[r][2], redm[r][3]));
  // ---- pass 2: per-thread Z partials for all 16 ranks, one batched reduction
  float zz[KTOP];
#pragma unroll
  for (int r = 0; r < KTOP; ++r) {
    double cr = (double)(1023 - 2 * r);
    double md = (double)mf[r];
    float z = 0.f;
#pragma unroll
    for (int k = 0; k < 4; ++k)
      z += __expf((float)(fma(cr, sj[k], -bj[k]) - md));
    zz[r] = z;
  }
#pragma unroll
  for (int off = 32; off; off >>= 1) {
#pragma unroll
    for (int r = 0; r < KTOP; ++r) zz[r] += __shfl_down(zz[r], off, 64);
  }
  if (lane == 0) {
#pragma unroll
    for (int r = 0; r < KTOP; ++r) redz[r][wave] = zz[r];
  }
  __syncthreads();
  // ---- pass 3: accumulate in original r order (bitwise-identical acc)
#pragma unroll
  for (int r = 0; r < KTOP; ++r) {
    double cr = (double)(1023 - 2 * r);
    double md = (double)mf[r];
    float iZ = 1.0f / ((redz[r][0] + redz[r][1]) + (redz[r][2] + redz[r][3]));
#pragma unroll
    for (int k = 0; k < 4; ++k)
      acc[k] += __expf((float)(fma(cr, sj[k], -bj[k]) - md)) * iZ;
  }
#pragma unroll
  for (int k = 0; k < 4; ++k) out[base + tid + k * 256] = acc[k];
}

extern "C" void kernel_launch(void* const* d_in, const int* in_sizes, int n_in,
                              void* d_out, int out_size, void* d_ws, size_t ws_size,
                              hipStream_t stream) {
  const float* q   = (const float*)d_in[0];   // [32,128]
  const float* nb  = (const float*)d_in[1];   // [1024,128]
  const float* gum = (const float*)d_in[2];   // [2,32,1024]
  float* out = (float*)d_out;                 // [2,32,1024]

  char* ws = (char*)d_ws;
  double* s = (double*)ws;                          // 512 KiB
  double* B = (double*)(ws + (size_t)NP * NN * 8);  // 512 KiB

  k_sb<<<256, 256, 0, stream>>>(q, nb, gum, s, B);
  k_soft<<<NP, 256, 0, stream>>>(s, B, out);
}

// Round 3
// 75.750 us; speedup vs baseline: 1.5724x; 1.1795x over previous
//
#include <hip/hip_runtime.h>

// DKNN via NeuralSort relaxation — round 6 (best-of-both recombination).
// query [32,128] f32, neighbors [1024,128] f32, gumbel [2,32,1024] f32.
// out [2,32,1024] f32 = sum of first K=16 rows of relaxed perm matrix.
//
// Numerics FROZEN (absmax pinned at 0.0234375, bf16 compare). Components:
//  - k_scores: exact R3 kernel (bit-proven).
//  - k_bsum:   exact R3 kernel (bit-proven). 1024 blocks = full device,
//              4 waves/SIMD — hides LDS broadcast-read latency (the R5
//              fusion dropped this to 1 wave/SIMD and lost ~15 us).
//  - k_soft:   R5's 2-barrier batched-reduction version (bit-proven),
//              with R3's Bq quarter-combine expression restored.
// All accumulation chains order-identical to R3 => bitwise-identical output.
//
// Timed-region floor: harness poison-fill of the 256 MiB workspace is
// ~40 us/iter (top-5 counter rows, WRITE_SIZE=262144 KB) — untouchable.
// Goal this round: kernels+gaps ~42 us (R3) -> ~18 us.

constexpr int NN = 1024;   // neighbors
constexpr int ND = 128;    // dims
constexpr int NP = 64;     // samples(2) * queries(32)
constexpr int KTOP = 16;

// ---------------------------------------------------------------- kernel 1
// s[p][j] = gumbel[p][j] - ||q_m - n_j||^2, all-f64. 256 blocks x 256 thr.
__global__ __launch_bounds__(256) void k_scores(const float* __restrict__ q,
                                                const float* __restrict__ nb,
                                                const float* __restrict__ gum,
                                                double* __restrict__ s_out) {
  int b = blockIdx.x;
  int p = b >> 2, chunk = b & 3;
  int m = p & 31;
  __shared__ double qs[ND];
  int tid = threadIdx.x;
  if (tid < ND) qs[tid] = (double)q[m * ND + tid];
  __syncthreads();
  int j = chunk * 256 + tid;
  const float4* nrow = (const float4*)(nb + (size_t)j * ND);
  double a0 = 0.0, a1 = 0.0, a2 = 0.0, a3 = 0.0;
#pragma unroll
  for (int d4 = 0; d4 < ND / 4; ++d4) {
    float4 n4 = nrow[d4];
    double d0 = qs[d4 * 4 + 0] - (double)n4.x;
    double d1 = qs[d4 * 4 + 1] - (double)n4.y;
    double d2 = qs[d4 * 4 + 2] - (double)n4.z;
    double d3 = qs[d4 * 4 + 3] - (double)n4.w;
    a0 += d0 * d0; a1 += d1 * d1; a2 += d2 * d2; a3 += d3 * d3;
  }
  s_out[(size_t)p * NN + j] =
      (double)gum[(size_t)p * NN + j] - ((a0 + a1) + (a2 + a3));
}

// ---------------------------------------------------------------- kernel 2
// B quarter-sums: Bq[iq][p][j] = sum_{i in quarter iq} |s_j - s_i|.
// grid = 64p * 4jchunk * 4iq = 1024 blocks x 256 thr (full device).
__global__ __launch_bounds__(256) void k_bsum(const double* __restrict__ s,
                                              double* __restrict__ Bq) {
  int b = blockIdx.x;
  int p = b >> 4, jc = (b >> 2) & 3, iq = b & 3;
  __shared__ double ss[256];
  int tid = threadIdx.x;
  ss[tid] = s[(size_t)p * NN + iq * 256 + tid];
  __syncthreads();
  double sj = s[(size_t)p * NN + jc * 256 + tid];
  double a0 = 0.0, a1 = 0.0, a2 = 0.0, a3 = 0.0;
#pragma unroll 4
  for (int i = 0; i < 256; i += 4) {
    a0 += fabs(sj - ss[i + 0]);
    a1 += fabs(sj - ss[i + 1]);
    a2 += fabs(sj - ss[i + 2]);
    a3 += fabs(sj - ss[i + 3]);
  }
  Bq[((size_t)iq * NP + p) * NN + jc * 256 + tid] = (a0 + a1) + (a2 + a3);
}

// ---------------------------------------------------------------- kernel 3
// Softmax-topk with 2 barriers total (R5 structure): pass 1 reduces all 16
// row maxes at once; pass 2 reduces all 16 Z's at once; pass 3 accumulates
// in original r order. t/e recomputed per pass — identical fp ops =>
// identical bits. bj combine = R3's (q0+q1)+(q2+q3) expression.
__global__ __launch_bounds__(256) void k_soft(const double* __restrict__ s,
                                              const double* __restrict__ Bq,
                                              float* __restrict__ out) {
  int p = blockIdx.x;
  int tid = threadIdx.x;
  int wave = tid >> 6, lane = tid & 63;
  const size_t QS = (size_t)NP * NN;
  size_t base = (size_t)p * NN;
  double sj[4], bj[4];
  float acc[4];
#pragma unroll
  for (int k = 0; k < 4; ++k) {
    size_t idx = base + tid + k * 256;
    sj[k] = s[idx];
    bj[k] = (Bq[idx] + Bq[QS + idx]) + (Bq[2 * QS + idx] + Bq[3 * QS + idx]);
    acc[k] = 0.f;
  }
  __shared__ float redm[KTOP][4];
  __shared__ float redz[KTOP][4];
  // ---- pass 1: per-thread maxes for all 16 ranks, one batched reduction
  float mx[KTOP];
#pragma unroll
  for (int r = 0; r < KTOP; ++r) {
    double cr = (double)(1023 - 2 * r);
    float mv = -3.4e38f;
#pragma unroll
    for (int k = 0; k < 4; ++k) mv = fmaxf(mv, (float)fma(cr, sj[k], -bj[k]));
    mx[r] = mv;
  }
#pragma unroll
  for (int off = 32; off; off >>= 1) {
#pragma unroll
    for (int r = 0; r < KTOP; ++r)
      mx[r] = fmaxf(mx[r], __shfl_down(mx[r], off, 64));
  }
  if (lane == 0) {
#pragma unroll
    for (int r = 0; r < KTOP; ++r) redm[r][wave] = mx[r];
  }
  __syncthreads();
  float mf[KTOP];
#pragma unroll
  for (int r = 0; r < KTOP; ++r)
    mf[r] = fmaxf(fmaxf(redm[r][0], redm[r][1]),
                  fmaxf(redm[r][2], redm[r][3]));
  // ---- pass 2: per-thread Z partials for all 16 ranks, one batched reduction
  float zz[KTOP];
#pragma unroll
  for (int r = 0; r < KTOP; ++r) {
    double cr = (double)(1023 - 2 * r);
    double md = (double)mf[r];
    float z = 0.f;
#pragma unroll
    for (int k = 0; k < 4; ++k)
      z += __expf((float)(fma(cr, sj[k], -bj[k]) - md));
    zz[r] = z;
  }
#pragma unroll
  for (int off = 32; off; off >>= 1) {
#pragma unroll
    for (int r = 0; r < KTOP; ++r) zz[r] += __shfl_down(zz[r], off, 64);
  }
  if (lane == 0) {
#pragma unroll
    for (int r = 0; r < KTOP; ++r) redz[r][wave] = zz[r];
  }
  __syncthreads();
  // ---- pass 3: accumulate in original r order (bitwise-identical acc)
#pragma unroll
  for (int r = 0; r < KTOP; ++r) {
    double cr = (double)(1023 - 2 * r);
    double md = (double)mf[r];
    float iZ = 1.0f / ((redz[r][0] + redz[r][1]) + (redz[r][2] + redz[r][3]));
#pragma unroll
    for (int k = 0; k < 4; ++k)
      acc[k] += __expf((float)(fma(cr, sj[k], -bj[k]) - md)) * iZ;
  }
#pragma unroll
  for (int k = 0; k < 4; ++k) out[base + tid + k * 256] = acc[k];
}

extern "C" void kernel_launch(void* const* d_in, const int* in_sizes, int n_in,
                              void* d_out, int out_size, void* d_ws, size_t ws_size,
                              hipStream_t stream) {
  const float* q   = (const float*)d_in[0];   // [32,128]
  const float* nb  = (const float*)d_in[1];   // [1024,128]
  const float* gum = (const float*)d_in[2];   // [2,32,1024]
  float* out = (float*)d_out;                 // [2,32,1024]

  char* ws = (char*)d_ws;
  double* s  = (double*)ws;                              // 512 KiB
  double* Bq = (double*)(ws + (size_t)NP * NN * 8);      // 4 x 512 KiB

  k_scores<<<256, 256, 0, stream>>>(q, nb, gum, s);
  k_bsum<<<1024, 256, 0, stream>>>(s, Bq);
  k_soft<<<NP, 256, 0, stream>>>(s, Bq, out);
}